// Round 13
// baseline (98.920 us; speedup 1.0000x reference)
//
#include <hip/hip_runtime.h>
#include <stdint.h>

#define T_STEPS 2048
#define NCHUNK  86            // 85 full 24-step chunks + one 8-step tail
#define LARGEF  1.0e9f
#define NB      512
typedef unsigned long long u64;
typedef unsigned uint2v __attribute__((ext_vector_type(2)));
typedef float f32x2 __attribute__((ext_vector_type(2)));

__device__ __forceinline__ int par6(int x) { return __builtin_popcount((unsigned)x) & 1; }

// dual-basis functionals C; exchange masks m={1,2,7,15,16,32} (verified r2-r12)
constexpr int CARR[6] = {5, 6, 12, 8, 16, 32};
constexpr int MARR[6] = {1, 2, 7, 15, 16, 32};

template<int CTRL>
__device__ __forceinline__ float xdpp(float x) {
  return __int_as_float(__builtin_amdgcn_update_dpp(0, __float_as_int(x), CTRL, 0xF, 0xF, true));
}
template<int CTRL>
__device__ __forceinline__ unsigned xdpp_u(unsigned x) {
  return (unsigned)__builtin_amdgcn_update_dpp(0, (int)x, CTRL, 0xF, 0xF, true);
}
__device__ __forceinline__ unsigned selmask_u(unsigned a_false, unsigned b_true, u64 m) {
  unsigned out;
  asm("v_cndmask_b32 %0, %1, %2, %3" : "=v"(out) : "v"(a_false), "v"(b_true), "s"(m));
  return out;
}
__device__ __forceinline__ unsigned exch16_u(unsigned x, u64 mrx) {
#if __has_builtin(__builtin_amdgcn_permlane16_swap)
  uint2v r = __builtin_amdgcn_permlane16_swap(x, x, false, false);
  return selmask_u(r.y, r.x, mrx);
#else
  (void)mrx;
  return (unsigned)__builtin_amdgcn_ds_swizzle((int)x, 0x401F);
#endif
}
__device__ __forceinline__ unsigned exch32_u(unsigned x, u64 mrx) {
#if __has_builtin(__builtin_amdgcn_permlane32_swap)
  uint2v r = __builtin_amdgcn_permlane32_swap(x, x, false, false);
  return selmask_u(r.y, r.x, mrx);
#else
  (void)mrx;
  return (unsigned)__shfl_xor((int)x, 32, 64);
#endif
}
template<int PH>
__device__ __forceinline__ float exchf(float x, const u64 (&mrx)[2]) {
  if constexpr (PH == 0) return xdpp<0xB1>(x);        // xor 1
  else if constexpr (PH == 1) return xdpp<0x4E>(x);   // xor 2
  else if constexpr (PH == 2) return xdpp<0x141>(x);  // xor 7
  else if constexpr (PH == 3) return xdpp<0x140>(x);  // xor 15
  else if constexpr (PH == 4) return __uint_as_float(exch16_u(__float_as_uint(x), mrx[0]));
  else return __uint_as_float(exch32_u(__float_as_uint(x), mrx[1]));
}
template<int PH>
__device__ __forceinline__ unsigned exchu(unsigned x, const u64 (&mrx)[2]) {
  if constexpr (PH == 0) return xdpp_u<0xB1>(x);
  else if constexpr (PH == 1) return xdpp_u<0x4E>(x);
  else if constexpr (PH == 2) return xdpp_u<0x141>(x);
  else if constexpr (PH == 3) return xdpp_u<0x140>(x);
  else if constexpr (PH == 4) return exch16_u(x, mrx[0]);
  else return exch32_u(x, mrx[1]);
}

struct Phc {
  float sae[6], sbe[6];
  unsigned sgn[6];   // pd ? 0 : 0x80000000 (sign-xor decision)
  unsigned pdu[6];   // decoded-bit constant per phase
  u64 pdm[6];        // uniform mask: lanes with odd own-pred parity
  u64 mrx[2];        // permlane swap r.x-select masks
};

__device__ __forceinline__ void mk_sasb(int lane, int ph, float& sae, float& sbe, int& pdv) {
  pdv = par6(lane & CARR[ph]);
  int t = 0;
#pragma unroll
  for (int j = 0; j < 5; ++j) t |= par6(lane & CARR[(ph + 1 + j) % 6]) << j;
  t |= pdv << 5;
  const float sa = 1.0f - 2.0f * (float)par6(t & 45);   // poly 1011011
  const float sb = 1.0f - 2.0f * (float)par6(t & 60);   // poly 1111001
  sae = pdv ? -sa : sa;
  sbe = pdv ? -sb : sb;
}

__device__ __forceinline__ void mk_mrx(int lane, u64 (&mrx)[2]) {
  const u64 ODD16 = 0xFFFF0000FFFF0000ull, HI32 = 0xFFFFFFFF00000000ull;
#if __has_builtin(__builtin_amdgcn_permlane16_swap)
  {
    uint2v r = __builtin_amdgcn_permlane16_swap((unsigned)lane, (unsigned)lane, false, false);
    mrx[0] = (((unsigned)__builtin_amdgcn_readlane((int)r.x, 0) == 16u)) ? ~ODD16 : ODD16;
  }
#else
  mrx[0] = 0;
#endif
#if __has_builtin(__builtin_amdgcn_permlane32_swap)
  {
    uint2v r = __builtin_amdgcn_permlane32_swap((unsigned)lane, (unsigned)lane, false, false);
    mrx[1] = (((unsigned)__builtin_amdgcn_readlane((int)r.x, 0) == 32u)) ? ~HI32 : HI32;
  }
#else
  mrx[1] = 0;
#endif
}

__device__ __forceinline__ void mkconsts(int lane, Phc& p) {
#pragma unroll
  for (int ph = 0; ph < 6; ++ph) {
    int pdv;
    mk_sasb(lane, ph, p.sae[ph], p.sbe[ph], pdv);
    p.sgn[ph] = pdv ? 0u : 0x80000000u;
    p.pdu[ph] = (unsigned)pdv;
    p.pdm[ph] = __ballot(pdv != 0);
  }
  mk_mrx(lane, p.mrx);
}

// ---- terminal argmin over true states (tie -> smallest state) ----
__device__ __forceinline__ int term_argmin(float cum, int lane) {
  // final labeling = phase 2048%6 = 2: state bit j from C[(2+j)%6] = {12,8,16,32,5,6}
  const int stf = par6(lane & 12) | (par6(lane & 8) << 1) | (par6(lane & 16) << 2) |
                  (par6(lane & 32) << 3) | (par6(lane & 5) << 4) | (par6(lane & 6) << 5);
  float v = cum; int bs = stf; int bl = lane;
#pragma unroll
  for (int off = 32; off >= 1; off >>= 1) {
    const float ov = __shfl_xor(v, off, 64);
    const int os = __shfl_xor(bs, off, 64);
    const int ol = __shfl_xor(bl, off, 64);
    if (ov < v || (ov == v && os < bs)) { v = ov; bs = os; bl = ol; }
  }
  return bl;
}

// ---- K1 radix-4 round: 2 trellis steps, one exchange level (r8-verified algebra) ----
// c00p=cum+bmA  c01p=exA-bmA  c10p=exB+bmA2  c11p=exAB-bmA2
// u=min(c00p,c01p) v=min(c10p,c11p) ; cum'=min(u+bmB, v-bmB)  [exactness: RN monotone]
template<int NR, int R>
__device__ __forceinline__ void acs4(float& cum, const float4 (&fy)[12],
                                     const f32x2 (&sAp)[3], const f32x2 (&sAq)[3],
                                     const f32x2 (&s2p)[3], const f32x2 (&s2q)[3],
                                     const f32x2 (&sBp)[3], const f32x2 (&sBq)[3],
                                     const u64 (&mrx)[2]) {
  if constexpr (R < NR) {
    constexpr int RP = R % 3;
    f32x2 yA; yA.x = fy[R].x; yA.y = fy[R].y;
    f32x2 yB; yB.x = fy[R].z; yB.y = fy[R].w;
    f32x2 tA, bA, tA2, bA2, tB, bB;
    // (bm, -bm) via pk ops; op_sel encodings bit-verified in r12 (absmax 0)
    asm("v_pk_mul_f32 %0, %1, %2 op_sel:[0,1] op_sel_hi:[1,1]" : "=v"(tA) : "v"(sAq[RP]), "v"(yA));
    asm("v_pk_fma_f32 %0, %1, %2, %3 op_sel:[0,0,0] op_sel_hi:[1,0,1]" : "=v"(bA) : "v"(sAp[RP]), "v"(yA), "v"(tA));
    asm("v_pk_mul_f32 %0, %1, %2 op_sel:[0,1] op_sel_hi:[1,1]" : "=v"(tA2) : "v"(s2q[RP]), "v"(yA));
    asm("v_pk_fma_f32 %0, %1, %2, %3 op_sel:[0,0,0] op_sel_hi:[1,0,1]" : "=v"(bA2) : "v"(s2p[RP]), "v"(yA), "v"(tA2));
    asm("v_pk_mul_f32 %0, %1, %2 op_sel:[0,1] op_sel_hi:[1,1]" : "=v"(tB) : "v"(sBq[RP]), "v"(yB));
    asm("v_pk_fma_f32 %0, %1, %2, %3 op_sel:[0,0,0] op_sel_hi:[1,0,1]" : "=v"(bB) : "v"(sBp[RP]), "v"(yB), "v"(tB));
    f32x2 ca, cb;   // (cum, exA), (exB, exAB) — all exchanges on the same cum
    ca.x = cum;
    if constexpr (RP == 0) {
      ca.y = xdpp<0xB1>(cum);          // xor 1
      cb.x = xdpp<0x4E>(cum);          // xor 2
      cb.y = xdpp<0x1B>(cum);          // xor 3
    } else if constexpr (RP == 1) {
      ca.y = xdpp<0x141>(cum);         // xor 7  (row_half_mirror)
      cb.x = xdpp<0x140>(cum);         // xor 15 (row_mirror)
      cb.y = xdpp<0x128>(cum);         // xor 8  (row_ror:8 == xor8; r8-verified)
    } else {
      ca.y = __uint_as_float(exch16_u(__float_as_uint(cum), mrx[0]));   // xor 16
      cb.x = __uint_as_float(exch32_u(__float_as_uint(cum), mrx[1]));   // xor 32
      cb.y = __uint_as_float(exch16_u(__float_as_uint(cb.x), mrx[0]));  // xor 48
    }
    f32x2 pp, qq, uv, xy;
    asm("v_pk_add_f32 %0, %1, %2" : "=v"(pp) : "v"(ca), "v"(bA));
    asm("v_pk_add_f32 %0, %1, %2" : "=v"(qq) : "v"(cb), "v"(bA2));
    uv.x = fminf(pp.x, pp.y);
    uv.y = fminf(qq.x, qq.y);
    asm("v_pk_add_f32 %0, %1, %2" : "=v"(xy) : "v"(uv), "v"(bB));
    cum = fminf(xy.x, xy.y);
    acs4<NR, R + 1>(cum, fy, sAp, sAq, s2p, s2q, sBp, sBq, mrx);
  }
}

// ---- K23 redo step: r9-verified full step with fused word reconstruction ----
template<int KB, int N, int K>
__device__ __forceinline__ void rstep(float& cum, unsigned& word, const float4 (&fy)[4],
                                      const Phc& p) {
  if constexpr (K < N) {
    constexpr int ph = (KB + K) % 6;
    const float y0 = (K & 1) ? fy[K >> 1].z : fy[K >> 1].x;
    const float y1 = (K & 1) ? fy[K >> 1].w : fy[K >> 1].y;
    const float bm = fmaf(p.sae[ph], y0, p.sbe[ph] * y1);   // bit-exact vs ref & K1
    const float ex = exchf<ph>(cum, p.mrx);
    const unsigned exw = exchu<ph>(word, p.mrx);
    const float cA = cum + bm;
    const float cB = ex - bm;
    const float D = cA - cB;
    cum = fminf(cA, cB);
    const unsigned w0 = selmask_u(word, exw, p.pdm[ph]);
    const unsigned w1 = selmask_u(exw, word, p.pdm[ph]);
    const bool d = __uint_as_float(__float_as_uint(D) ^ p.sgn[ph]) < 0.0f;
    word = (d ? w1 : w0) | (p.pdu[ph] << (6 + KB + K));
    rstep<KB, N, K + 1>(cum, word, fy, p);
  }
}

// ============== K1: radix-4 forward, cum checkpoints only (no decisions) ==============
__global__ __launch_bounds__(64, 1) void vit_fwd(const float* __restrict__ in,
                                                 float* __restrict__ cp) {
  __shared__ float y_lds[2 * T_STEPS];   // 16 KB staged input row
  const int b = blockIdx.x;
  const int lane = threadIdx.x;
  {
    const float4* g = (const float4*)(in + (size_t)b * (2 * T_STEPS));
    float4* l = (float4*)y_lds;
#pragma unroll
    for (int i = 0; i < 16; ++i) l[i * 64 + lane] = g[i * 64 + lane];
  }
  __syncthreads();

  f32x2 sAp[3], sAq[3], s2p[3], s2q[3], sBp[3], sBq[3];
  u64 mrx[2];
#pragma unroll
  for (int rp = 0; rp < 3; ++rp) {
    const int pA = 2 * rp, pB = 2 * rp + 1;
    const int mB = MARR[pB];                 // 2, 15, 32
    float sa, sb; int pd;
    mk_sasb(lane, pA, sa, sb, pd);
    sAp[rp].x = sa; sAp[rp].y = -sa; sAq[rp].x = sb; sAq[rp].y = -sb;
    mk_sasb(lane ^ mB, pA, sa, sb, pd);
    s2p[rp].x = sa; s2p[rp].y = -sa; s2q[rp].x = sb; s2q[rp].y = -sb;
    mk_sasb(lane, pB, sa, sb, pd);
    sBp[rp].x = sa; sBp[rp].y = -sa; sBq[rp].x = sb; sBq[rp].y = -sb;
  }
  mk_mrx(lane, mrx);

  float cum = (lane == 0) ? 0.0f : LARGEF;
  float4 cur[12], nxt[12];
  const float4* y4 = (const float4*)y_lds;
  float* cpp = cp + (size_t)b * (NCHUNK * 64) + lane;
#pragma unroll
  for (int j = 0; j < 12; ++j) cur[j] = y4[j];               // chunk 0
  for (int cc = 0; cc < 42; ++cc) {
    const int c0 = 2 * cc;
#pragma unroll
    for (int j = 0; j < 12; ++j) nxt[j] = y4[12 * (c0 + 1) + j];   // prefetch c0+1
    acs4<12, 0>(cum, cur, sAp, sAq, s2p, s2q, sBp, sBq, mrx);
    cpp[c0 * 64] = cum;
#pragma unroll
    for (int j = 0; j < 12; ++j) cur[j] = y4[12 * (c0 + 2) + j];   // prefetch c0+2
    acs4<12, 0>(cum, nxt, sAp, sAq, s2p, s2q, sBp, sBq, mrx);
    cpp[(c0 + 1) * 64] = cum;
  }
  // cur = chunk 84; tail (steps 2040..2047) = float4 idx 1020..1023
#pragma unroll
  for (int j = 0; j < 4; ++j) nxt[j] = y4[1020 + j];
  acs4<12, 0>(cum, cur, sAp, sAq, s2p, s2q, sBp, sBq, mrx);
  cpp[84 * 64] = cum;
  acs4<4, 0>(cum, nxt, sAp, sAq, s2p, s2q, sBp, sBq, mrx);
  cpp[85 * 64] = cum;
}

// ====== K23: per-chunk decision recompute (8 waves, no spills) + wave0 traceback ======
__global__ __launch_bounds__(512, 1) void vit_rc(const float* __restrict__ in,
                                                 const float* __restrict__ cp,
                                                 float* __restrict__ out) {
  __shared__ float y_lds[2 * T_STEPS];     // 16 KB
  __shared__ unsigned tbf[NCHUNK][64];     // 21.5 KB path/anc words
  const int tid = threadIdx.x;
  const int lane = tid & 63;
  const int wv = tid >> 6;
  const int b = blockIdx.x;
  {
    const float4* g = (const float4*)(in + (size_t)b * (2 * T_STEPS));
    float4* l = (float4*)y_lds;
    l[tid] = g[tid];
    l[tid + 512] = g[tid + 512];
  }
  Phc p;
  mkconsts(lane, p);
  __syncthreads();

  const int cbeg = wv * 11;
  const int cend = (cbeg + 11 < NCHUNK) ? cbeg + 11 : NCHUNK;
  for (int c = cbeg; c < cend; ++c) {
    float cum = (c == 0) ? ((lane == 0) ? 0.0f : LARGEF)
                         : cp[(size_t)b * (NCHUNK * 64) + (c - 1) * 64 + lane];
    unsigned word = (unsigned)lane;
    const float4* yc = ((const float4*)y_lds) + 12 * c;
    if (c != NCHUNK - 1) {
      float4 fy[4];
#pragma unroll
      for (int j = 0; j < 4; ++j) fy[j] = yc[j];
      rstep<0, 8, 0>(cum, word, fy, p);
#pragma unroll
      for (int j = 0; j < 4; ++j) fy[j] = yc[4 + j];
      rstep<8, 8, 0>(cum, word, fy, p);
#pragma unroll
      for (int j = 0; j < 4; ++j) fy[j] = yc[8 + j];
      rstep<16, 8, 0>(cum, word, fy, p);
    } else {
      float4 fy[4];
#pragma unroll
      for (int j = 0; j < 4; ++j) fy[j] = yc[j];
      rstep<0, 8, 0>(cum, word, fy, p);   // tail: 8 steps
    }
    tbf[c][lane] = word;
  }
  __syncthreads();

  if (wv == 0) {
    const float cumF = cp[(size_t)b * (NCHUNK * 64) + 85 * 64 + lane];
    int lam = __builtin_amdgcn_readfirstlane(term_argmin(cumF, lane));
    const size_t ob = (size_t)b * T_STEPS;
    unsigned row = tbf[NCHUNK - 1][lane];
    for (int c = NCHUNK - 1; c >= 0; --c) {
      unsigned nrow = 0;
      if (c > 0) nrow = tbf[c - 1][lane];          // prefetch (addr indep of lam)
      const unsigned w = (unsigned)__builtin_amdgcn_readlane((int)row, lam);
      const int nb = (c == NCHUNK - 1) ? 8 : 24;
      if (lane < nb) out[ob + c * 24 + lane] = (float)((w >> (6 + lane)) & 1u);
      lam = (int)(w & 63u);
      row = nrow;
    }
  }
}

// ====== fallback: r9-proven single-kernel path (used if ws too small) ======
template<int N, int K>
__device__ __forceinline__ void fb_step(float& cum, unsigned& word, const float (&bm)[24],
                                        const Phc& p) {
  if constexpr (K < N) {
    constexpr int ph = K % 6;
    const float ex = exchf<ph>(cum, p.mrx);
    const unsigned exw = exchu<ph>(word, p.mrx);
    const float cA = cum + bm[K];
    const float cB = ex - bm[K];
    const float D = cA - cB;
    cum = fminf(cA, cB);
    const unsigned w0 = selmask_u(word, exw, p.pdm[ph]);
    const unsigned w1 = selmask_u(exw, word, p.pdm[ph]);
    const bool d = __uint_as_float(__float_as_uint(D) ^ p.sgn[ph]) < 0.0f;
    word = (d ? w1 : w0) | (p.pdu[ph] << (6 + K));
    fb_step<N, K + 1>(cum, word, bm, p);
  }
}
template<int N>
__device__ __forceinline__ void fb_bm(const float4 (&fy)[12], float (&bm)[24], const Phc& p) {
#pragma unroll
  for (int k = 0; k < N; ++k) {
    const int ph = k % 6;
    const float y0 = (k & 1) ? fy[k >> 1].z : fy[k >> 1].x;
    const float y1 = (k & 1) ? fy[k >> 1].w : fy[k >> 1].y;
    bm[k] = fmaf(p.sae[ph], y0, p.sbe[ph] * y1);
  }
}
__global__ __launch_bounds__(64, 1) void vit_fb(const float* __restrict__ in,
                                                float* __restrict__ out) {
  __shared__ float y_lds[2 * T_STEPS];
  __shared__ unsigned tbf[NCHUNK][64];
  const int b = blockIdx.x;
  const int lane = threadIdx.x;
  {
    const float4* g = (const float4*)(in + (size_t)b * (2 * T_STEPS));
    float4* l = (float4*)y_lds;
#pragma unroll
    for (int i = 0; i < 16; ++i) l[i * 64 + lane] = g[i * 64 + lane];
  }
  __syncthreads();
  Phc p;
  mkconsts(lane, p);
  float cum = (lane == 0) ? 0.0f : LARGEF;
  unsigned word = (unsigned)lane;
  float bm[24];
  float4 cur[12], nxt[12];
  const float4* y4 = (const float4*)y_lds;
#pragma unroll
  for (int j = 0; j < 12; ++j) cur[j] = y4[j];
  for (int cc = 0; cc < 42; ++cc) {
    const int c0 = 2 * cc;
    fb_bm<24>(cur, bm, p);
#pragma unroll
    for (int j = 0; j < 12; ++j) nxt[j] = y4[12 * (c0 + 1) + j];
    fb_step<24, 0>(cum, word, bm, p);
    tbf[c0][lane] = word; word = (unsigned)lane;
    fb_bm<24>(nxt, bm, p);
#pragma unroll
    for (int j = 0; j < 12; ++j) cur[j] = y4[12 * (c0 + 2) + j];
    fb_step<24, 0>(cum, word, bm, p);
    tbf[c0 + 1][lane] = word; word = (unsigned)lane;
  }
  fb_bm<24>(cur, bm, p);
#pragma unroll
  for (int j = 0; j < 4; ++j) nxt[j] = y4[1020 + j];
  fb_step<24, 0>(cum, word, bm, p);
  tbf[84][lane] = word; word = (unsigned)lane;
  fb_bm<8>(nxt, bm, p);
  fb_step<8, 0>(cum, word, bm, p);
  tbf[85][lane] = word;

  int lam = __builtin_amdgcn_readfirstlane(term_argmin(cum, lane));
  const size_t ob = (size_t)b * T_STEPS;
  unsigned row = tbf[85][lane];
  for (int c = 85; c >= 0; --c) {
    unsigned nrow = 0;
    if (c > 0) nrow = tbf[c - 1][lane];
    const unsigned w = (unsigned)__builtin_amdgcn_readlane((int)row, lam);
    const int nb = (c == 85) ? 8 : 24;
    if (lane < nb) out[ob + c * 24 + lane] = (float)((w >> (6 + lane)) & 1u);
    lam = (int)(w & 63u);
    row = nrow;
  }
}

extern "C" void kernel_launch(void* const* d_in, const int* in_sizes, int n_in,
                              void* d_out, int out_size, void* d_ws, size_t ws_size,
                              hipStream_t stream) {
  const float* in = (const float*)d_in[0];
  float* out = (float*)d_out;
  (void)in_sizes; (void)n_in; (void)out_size;
  const size_t need = (size_t)NB * NCHUNK * 64 * 4;   // 11.3 MB checkpoints
  if (ws_size >= need) {
    float* cp = (float*)d_ws;
    vit_fwd<<<dim3(NB), dim3(64), 0, stream>>>(in, cp);
    vit_rc<<<dim3(NB), dim3(512), 0, stream>>>(in, cp, out);
  } else {
    vit_fb<<<dim3(NB), dim3(64), 0, stream>>>(in, out);
  }
}

// Round 14
// 70.198 us; speedup vs baseline: 1.4092x; 1.4092x over previous
//
#include <hip/hip_runtime.h>
#include <stdint.h>

#define T_STEPS 2048
#define NCHUNK  86            // 85 full 24-step chunks + one 8-step tail
#define LARGEF  1.0e9f
#define NB      512
typedef unsigned long long u64;
typedef unsigned uint2v __attribute__((ext_vector_type(2)));

__device__ __forceinline__ int par6(int x) { return __builtin_popcount((unsigned)x) & 1; }

// dual-basis functionals C; exchange masks m={1,2,7,15,16,32} (verified r2-r13)
constexpr int CARR[6] = {5, 6, 12, 8, 16, 32};

template<int CTRL>
__device__ __forceinline__ float xdpp(float x) {
  return __int_as_float(__builtin_amdgcn_update_dpp(0, __float_as_int(x), CTRL, 0xF, 0xF, true));
}
template<int CTRL>
__device__ __forceinline__ unsigned xdpp_u(unsigned x) {
  return (unsigned)__builtin_amdgcn_update_dpp(0, (int)x, CTRL, 0xF, 0xF, true);
}
__device__ __forceinline__ unsigned selmask_u(unsigned a_false, unsigned b_true, u64 m) {
  unsigned out;
  asm("v_cndmask_b32 %0, %1, %2, %3" : "=v"(out) : "v"(a_false), "v"(b_true), "s"(m));
  return out;
}
__device__ __forceinline__ unsigned exch16_u(unsigned x, u64 mrx) {
#if __has_builtin(__builtin_amdgcn_permlane16_swap)
  uint2v r = __builtin_amdgcn_permlane16_swap(x, x, false, false);
  return selmask_u(r.y, r.x, mrx);
#else
  (void)mrx;
  return (unsigned)__builtin_amdgcn_ds_swizzle((int)x, 0x401F);
#endif
}
__device__ __forceinline__ unsigned exch32_u(unsigned x, u64 mrx) {
#if __has_builtin(__builtin_amdgcn_permlane32_swap)
  uint2v r = __builtin_amdgcn_permlane32_swap(x, x, false, false);
  return selmask_u(r.y, r.x, mrx);
#else
  (void)mrx;
  return (unsigned)__shfl_xor((int)x, 32, 64);
#endif
}
template<int PH>
__device__ __forceinline__ float exchf(float x, const u64 (&mrx)[2]) {
  if constexpr (PH == 0) return xdpp<0xB1>(x);        // xor 1
  else if constexpr (PH == 1) return xdpp<0x4E>(x);   // xor 2
  else if constexpr (PH == 2) return xdpp<0x141>(x);  // xor 7
  else if constexpr (PH == 3) return xdpp<0x140>(x);  // xor 15
  else if constexpr (PH == 4) return __uint_as_float(exch16_u(__float_as_uint(x), mrx[0]));
  else return __uint_as_float(exch32_u(__float_as_uint(x), mrx[1]));
}
template<int PH>
__device__ __forceinline__ unsigned exchu(unsigned x, const u64 (&mrx)[2]) {
  if constexpr (PH == 0) return xdpp_u<0xB1>(x);
  else if constexpr (PH == 1) return xdpp_u<0x4E>(x);
  else if constexpr (PH == 2) return xdpp_u<0x141>(x);
  else if constexpr (PH == 3) return xdpp_u<0x140>(x);
  else if constexpr (PH == 4) return exch16_u(x, mrx[0]);
  else return exch32_u(x, mrx[1]);
}

struct Phc {
  float sae[6], sbe[6];
  unsigned sgn[6];   // pd ? 0 : 0x80000000 (sign-xor decision)
  unsigned pdu[6];   // decoded-bit constant per phase
  u64 pdm[6];        // uniform mask: lanes with odd own-pred parity
  u64 mrx[2];        // permlane swap r.x-select masks
};

__device__ __forceinline__ void mk_sasb(int lane, int ph, float& sae, float& sbe, int& pdv) {
  pdv = par6(lane & CARR[ph]);
  int t = 0;
#pragma unroll
  for (int j = 0; j < 5; ++j) t |= par6(lane & CARR[(ph + 1 + j) % 6]) << j;
  t |= pdv << 5;
  const float sa = 1.0f - 2.0f * (float)par6(t & 45);   // poly 1011011
  const float sb = 1.0f - 2.0f * (float)par6(t & 60);   // poly 1111001
  sae = pdv ? -sa : sa;
  sbe = pdv ? -sb : sb;
}

__device__ __forceinline__ void mk_mrx(int lane, u64 (&mrx)[2]) {
  const u64 ODD16 = 0xFFFF0000FFFF0000ull, HI32 = 0xFFFFFFFF00000000ull;
#if __has_builtin(__builtin_amdgcn_permlane16_swap)
  {
    uint2v r = __builtin_amdgcn_permlane16_swap((unsigned)lane, (unsigned)lane, false, false);
    mrx[0] = (((unsigned)__builtin_amdgcn_readlane((int)r.x, 0) == 16u)) ? ~ODD16 : ODD16;
  }
#else
  mrx[0] = 0;
#endif
#if __has_builtin(__builtin_amdgcn_permlane32_swap)
  {
    uint2v r = __builtin_amdgcn_permlane32_swap((unsigned)lane, (unsigned)lane, false, false);
    mrx[1] = (((unsigned)__builtin_amdgcn_readlane((int)r.x, 0) == 32u)) ? ~HI32 : HI32;
  }
#else
  mrx[1] = 0;
#endif
}

__device__ __forceinline__ void mkconsts(int lane, Phc& p) {
#pragma unroll
  for (int ph = 0; ph < 6; ++ph) {
    int pdv;
    mk_sasb(lane, ph, p.sae[ph], p.sbe[ph], pdv);
    p.sgn[ph] = pdv ? 0u : 0x80000000u;
    p.pdu[ph] = (unsigned)pdv;
    p.pdm[ph] = __ballot(pdv != 0);
  }
  mk_mrx(lane, p.mrx);
}

// ---- hoisted branch metrics for a chunk (independent ILP block) ----
template<int N>
__device__ __forceinline__ void bmcalc(const float4 (&fy)[12], float (&bm)[24],
                                       const float (&sae)[6], const float (&sbe)[6]) {
#pragma unroll
  for (int k = 0; k < N; ++k) {
    const int ph = k % 6;
    const float y0 = (k & 1) ? fy[k >> 1].z : fy[k >> 1].x;
    const float y1 = (k & 1) ? fy[k >> 1].w : fy[k >> 1].y;
    bm[k] = fmaf(sae[ph], y0, sbe[ph] * y1);   // bit-exact vs ref
  }
}

// ---- forward core: N ACS steps; dw = 2*dw + d (d_K lands at bit N-1-K) ----
template<int N, int K>
__device__ __forceinline__ void acs(float& cum, unsigned& dw, const float (&bm)[24],
                                    const unsigned (&sgn)[6], const u64 (&mrx)[2]) {
  if constexpr (K < N) {
    constexpr int ph = K % 6;
    const float ex = exchf<ph>(cum, mrx);
    const float cA = cum + bm[K];   // own-pred candidate
    const float cB = ex - bm[K];    // partner-pred candidate
    const float D = cA - cB;        // sign exact; zero iff true tie
    cum = fminf(cA, cB);
    unsigned tmp;
    asm("v_xor_b32 %0, %2, %3\n\t"
        "v_cmp_gt_f32 vcc, 0, %0\n\t"
        "v_addc_co_u32 %1, vcc, %1, %1, vcc"
        : "=&v"(tmp), "+v"(dw)
        : "v"(D), "v"(sgn[ph]) : "vcc");
    acs<N, K + 1>(cum, dw, bm, sgn, mrx);
  }
}

// ---- chunk word reconstruction from d-bits (tp = d XOR pd; verified r10/r11) ----
template<int N, int K>
__device__ __forceinline__ void wrec(unsigned& word, unsigned& dws, const unsigned (&pdu)[6],
                                     const u64 (&pdm)[6], const u64 (&mrx)[2]) {
  if constexpr (K < N) {
    constexpr int ph = K % 6;
    const unsigned exw = exchu<ph>(word, mrx);
    asm("v_cmp_gt_i32 vcc, 0, %1\n\t"
        "v_add_u32 %1, %1, %1\n\t"
        "s_xor_b64 vcc, vcc, %3\n\t"
        "v_cndmask_b32 %0, %0, %2, vcc"
        : "+v"(word), "+v"(dws)
        : "v"(exw), "s"(pdm[ph]) : "vcc");
    word |= pdu[ph] << (6 + K);
    wrec<N, K + 1>(word, dws, pdu, pdm, mrx);
  }
}

// ---- terminal argmin over true states (tie -> smallest state) ----
__device__ __forceinline__ int term_argmin(float cum, int lane) {
  // final labeling = phase 2048%6 = 2: state bit j from C[(2+j)%6] = {12,8,16,32,5,6}
  const int stf = par6(lane & 12) | (par6(lane & 8) << 1) | (par6(lane & 16) << 2) |
                  (par6(lane & 32) << 3) | (par6(lane & 5) << 4) | (par6(lane & 6) << 5);
  float v = cum; int bs = stf; int bl = lane;
#pragma unroll
  for (int off = 32; off >= 1; off >>= 1) {
    const float ov = __shfl_xor(v, off, 64);
    const int os = __shfl_xor(bs, off, 64);
    const int ol = __shfl_xor(bl, off, 64);
    if (ov < v || (ov == v && os < bs)) { v = ov; bs = os; bl = ol; }
  }
  return bl;
}

// ======= K1: forward pass (r11-verbatim, 50.7 us), d-bit planes + term to ws =======
__global__ __launch_bounds__(64, 1) void vit_fwd(const float* __restrict__ in,
                                                 unsigned* __restrict__ dwg,
                                                 int* __restrict__ term) {
  __shared__ float y_lds[2 * T_STEPS];   // 16 KB staged input row
  const int b = blockIdx.x;
  const int lane = threadIdx.x;
  {
    const float4* g = (const float4*)(in + (size_t)b * (2 * T_STEPS));
    float4* l = (float4*)y_lds;
#pragma unroll
    for (int i = 0; i < 16; ++i) l[i * 64 + lane] = g[i * 64 + lane];
  }
  __syncthreads();

  Phc p;
  mkconsts(lane, p);

  float cum = (lane == 0) ? 0.0f : LARGEF;
  float bm[24];
  float4 cur[12], nxt[12];
  const float4* y4 = (const float4*)y_lds;
  unsigned* dwp = dwg + (size_t)b * (NCHUNK * 64) + lane;
  unsigned dw;
#pragma unroll
  for (int j = 0; j < 12; ++j) cur[j] = y4[j];               // chunk 0
  for (int cc = 0; cc < 42; ++cc) {
    const int c0 = 2 * cc;
    bmcalc<24>(cur, bm, p.sae, p.sbe);
#pragma unroll
    for (int j = 0; j < 12; ++j) nxt[j] = y4[12 * (c0 + 1) + j];   // prefetch c0+1
    dw = 0; acs<24, 0>(cum, dw, bm, p.sgn, p.mrx);
    *dwp = dw; dwp += 64;
    bmcalc<24>(nxt, bm, p.sae, p.sbe);
#pragma unroll
    for (int j = 0; j < 12; ++j) cur[j] = y4[12 * (c0 + 2) + j];   // prefetch c0+2
    dw = 0; acs<24, 0>(cum, dw, bm, p.sgn, p.mrx);
    *dwp = dw; dwp += 64;
  }
  // chunk 84 from cur; tail (steps 2040..2047) = float4 idx 1020..1023
  bmcalc<24>(cur, bm, p.sae, p.sbe);
#pragma unroll
  for (int j = 0; j < 4; ++j) nxt[j] = y4[1020 + j];
  dw = 0; acs<24, 0>(cum, dw, bm, p.sgn, p.mrx);
  *dwp = dw; dwp += 64;
  bmcalc<8>(nxt, bm, p.sae, p.sbe);
  dw = 0; acs<8, 0>(cum, dw, bm, p.sgn, p.mrx);
  *dwp = dw;

  const int bl = term_argmin(cum, lane);
  if (lane == 0) term[b] = bl;
}

// ===== K23: merged word reconstruction (8 waves) + wave0 traceback, one launch =====
__global__ __launch_bounds__(512, 1) void vit_rc(const unsigned* __restrict__ dwg,
                                                 const int* __restrict__ term,
                                                 float* __restrict__ out) {
  __shared__ unsigned tbf[NCHUNK][64];   // 21.5 KB path/anc words
  const int tid = threadIdx.x;
  const int lane = tid & 63;
  const int wv = tid >> 6;
  const int b = blockIdx.x;

  unsigned pdu[6];
  u64 pdm[6], mrx[2];
#pragma unroll
  for (int ph = 0; ph < 6; ++ph) {
    const int pdv = par6(lane & CARR[ph]);
    pdu[ph] = (unsigned)pdv;
    pdm[ph] = __ballot(pdv != 0);
  }
  mk_mrx(lane, mrx);

  const int cbeg = wv * 11;
  const int cend = (cbeg + 11 < NCHUNK) ? cbeg + 11 : NCHUNK;
  for (int c = cbeg; c < cend; ++c) {
    const unsigned dw = dwg[((size_t)b * NCHUNK + c) * 64 + lane];
    unsigned word = (unsigned)lane;
    if (c == NCHUNK - 1) {
      unsigned dws = dw << 24;
      wrec<8, 0>(word, dws, pdu, pdm, mrx);
    } else {
      unsigned dws = dw << 8;
      wrec<24, 0>(word, dws, pdu, pdm, mrx);
    }
    tbf[c][lane] = word;
  }
  __syncthreads();

  if (wv == 0) {
    int lam = __builtin_amdgcn_readfirstlane(term[b]);
    const size_t ob = (size_t)b * T_STEPS;
    unsigned row = tbf[NCHUNK - 1][lane];
    for (int c = NCHUNK - 1; c >= 0; --c) {
      unsigned nrow = 0;
      if (c > 0) nrow = tbf[c - 1][lane];          // prefetch (addr indep of lam)
      const unsigned w = (unsigned)__builtin_amdgcn_readlane((int)row, lam);
      const int nb = (c == NCHUNK - 1) ? 8 : 24;
      if (lane < nb) out[ob + c * 24 + lane] = (float)((w >> (6 + lane)) & 1u);
      lam = (int)(w & 63u);
      row = nrow;
    }
  }
}

// ====== fallback: r9-proven single-kernel path (used if ws too small) ======
template<int N, int K>
__device__ __forceinline__ void fb_step(float& cum, unsigned& word, const float (&bm)[24],
                                        const Phc& p) {
  if constexpr (K < N) {
    constexpr int ph = K % 6;
    const float ex = exchf<ph>(cum, p.mrx);
    const unsigned exw = exchu<ph>(word, p.mrx);
    const float cA = cum + bm[K];
    const float cB = ex - bm[K];
    const float D = cA - cB;
    cum = fminf(cA, cB);
    const unsigned w0 = selmask_u(word, exw, p.pdm[ph]);
    const unsigned w1 = selmask_u(exw, word, p.pdm[ph]);
    const bool d = __uint_as_float(__float_as_uint(D) ^ p.sgn[ph]) < 0.0f;
    word = (d ? w1 : w0) | (p.pdu[ph] << (6 + K));
    fb_step<N, K + 1>(cum, word, bm, p);
  }
}
__global__ __launch_bounds__(64, 1) void vit_fb(const float* __restrict__ in,
                                                float* __restrict__ out) {
  __shared__ float y_lds[2 * T_STEPS];
  __shared__ unsigned tbf[NCHUNK][64];
  const int b = blockIdx.x;
  const int lane = threadIdx.x;
  {
    const float4* g = (const float4*)(in + (size_t)b * (2 * T_STEPS));
    float4* l = (float4*)y_lds;
#pragma unroll
    for (int i = 0; i < 16; ++i) l[i * 64 + lane] = g[i * 64 + lane];
  }
  __syncthreads();
  Phc p;
  mkconsts(lane, p);
  float cum = (lane == 0) ? 0.0f : LARGEF;
  unsigned word = (unsigned)lane;
  float bm[24];
  float4 cur[12], nxt[12];
  const float4* y4 = (const float4*)y_lds;
#pragma unroll
  for (int j = 0; j < 12; ++j) cur[j] = y4[j];
  for (int cc = 0; cc < 42; ++cc) {
    const int c0 = 2 * cc;
    bmcalc<24>(cur, bm, p.sae, p.sbe);
#pragma unroll
    for (int j = 0; j < 12; ++j) nxt[j] = y4[12 * (c0 + 1) + j];
    fb_step<24, 0>(cum, word, bm, p);
    tbf[c0][lane] = word; word = (unsigned)lane;
    bmcalc<24>(nxt, bm, p.sae, p.sbe);
#pragma unroll
    for (int j = 0; j < 12; ++j) cur[j] = y4[12 * (c0 + 2) + j];
    fb_step<24, 0>(cum, word, bm, p);
    tbf[c0 + 1][lane] = word; word = (unsigned)lane;
  }
  bmcalc<24>(cur, bm, p.sae, p.sbe);
#pragma unroll
  for (int j = 0; j < 4; ++j) nxt[j] = y4[1020 + j];
  fb_step<24, 0>(cum, word, bm, p);
  tbf[84][lane] = word; word = (unsigned)lane;
  bmcalc<8>(nxt, bm, p.sae, p.sbe);
  fb_step<8, 0>(cum, word, bm, p);
  tbf[85][lane] = word;

  int lam = __builtin_amdgcn_readfirstlane(term_argmin(cum, lane));
  const size_t ob = (size_t)b * T_STEPS;
  unsigned row = tbf[85][lane];
  for (int c = 85; c >= 0; --c) {
    unsigned nrow = 0;
    if (c > 0) nrow = tbf[c - 1][lane];
    const unsigned w = (unsigned)__builtin_amdgcn_readlane((int)row, lam);
    const int nb = (c == 85) ? 8 : 24;
    if (lane < nb) out[ob + c * 24 + lane] = (float)((w >> (6 + lane)) & 1u);
    lam = (int)(w & 63u);
    row = nrow;
  }
}

extern "C" void kernel_launch(void* const* d_in, const int* in_sizes, int n_in,
                              void* d_out, int out_size, void* d_ws, size_t ws_size,
                              hipStream_t stream) {
  const float* in = (const float*)d_in[0];
  float* out = (float*)d_out;
  (void)in_sizes; (void)n_in; (void)out_size;
  const size_t nwords = (size_t)NB * NCHUNK * 64;       // 2,818,048
  const size_t need = nwords * 4 + NB * 4;              // dwg + term (11.3 MB)
  if (ws_size >= need) {
    unsigned* dwg = (unsigned*)d_ws;
    int* term = (int*)(dwg + nwords);
    vit_fwd<<<dim3(NB), dim3(64), 0, stream>>>(in, dwg, term);
    vit_rc<<<dim3(NB), dim3(512), 0, stream>>>(dwg, term, out);
  } else {
    vit_fb<<<dim3(NB), dim3(64), 0, stream>>>(in, out);
  }
}

// Round 15
// 66.362 us; speedup vs baseline: 1.4906x; 1.0578x over previous
//
#include <hip/hip_runtime.h>
#include <stdint.h>

#define T_STEPS 2048
#define NCHUNK  86            // 85 full 24-step chunks + one 8-step tail
#define LARGEF  1.0e9f
#define NB      512
typedef unsigned long long u64;
typedef unsigned uint2v __attribute__((ext_vector_type(2)));

__device__ __forceinline__ int par6(int x) { return __builtin_popcount((unsigned)x) & 1; }

// dual-basis functionals C; exchange masks m={1,2,7,15,16,32} (verified r2-r14)
constexpr int CARR[6] = {5, 6, 12, 8, 16, 32};

template<int CTRL>
__device__ __forceinline__ float xdpp(float x) {
  return __int_as_float(__builtin_amdgcn_update_dpp(0, __float_as_int(x), CTRL, 0xF, 0xF, true));
}
template<int CTRL>
__device__ __forceinline__ unsigned xdpp_u(unsigned x) {
  return (unsigned)__builtin_amdgcn_update_dpp(0, (int)x, CTRL, 0xF, 0xF, true);
}
__device__ __forceinline__ unsigned selmask_u(unsigned a_false, unsigned b_true, u64 m) {
  unsigned out;
  asm("v_cndmask_b32 %0, %1, %2, %3" : "=v"(out) : "v"(a_false), "v"(b_true), "s"(m));
  return out;
}
__device__ __forceinline__ unsigned exch16_u(unsigned x, u64 mrx) {
#if __has_builtin(__builtin_amdgcn_permlane16_swap)
  uint2v r = __builtin_amdgcn_permlane16_swap(x, x, false, false);
  return selmask_u(r.y, r.x, mrx);
#else
  (void)mrx;
  return (unsigned)__builtin_amdgcn_ds_swizzle((int)x, 0x401F);
#endif
}
__device__ __forceinline__ unsigned exch32_u(unsigned x, u64 mrx) {
#if __has_builtin(__builtin_amdgcn_permlane32_swap)
  uint2v r = __builtin_amdgcn_permlane32_swap(x, x, false, false);
  return selmask_u(r.y, r.x, mrx);
#else
  (void)mrx;
  return (unsigned)__shfl_xor((int)x, 32, 64);
#endif
}
template<int PH>
__device__ __forceinline__ float exchf(float x, const u64 (&mrx)[2]) {
  if constexpr (PH == 0) return xdpp<0xB1>(x);        // xor 1
  else if constexpr (PH == 1) return xdpp<0x4E>(x);   // xor 2
  else if constexpr (PH == 2) return xdpp<0x141>(x);  // xor 7
  else if constexpr (PH == 3) return xdpp<0x140>(x);  // xor 15
  else if constexpr (PH == 4) return __uint_as_float(exch16_u(__float_as_uint(x), mrx[0]));
  else return __uint_as_float(exch32_u(__float_as_uint(x), mrx[1]));
}
template<int PH>
__device__ __forceinline__ unsigned exchu(unsigned x, const u64 (&mrx)[2]) {
  if constexpr (PH == 0) return xdpp_u<0xB1>(x);
  else if constexpr (PH == 1) return xdpp_u<0x4E>(x);
  else if constexpr (PH == 2) return xdpp_u<0x141>(x);
  else if constexpr (PH == 3) return xdpp_u<0x140>(x);
  else if constexpr (PH == 4) return exch16_u(x, mrx[0]);
  else return exch32_u(x, mrx[1]);
}

struct Phc {
  float sae[6], sbe[6];
  unsigned clsm[6];  // v_cmp_class mask: pd ? (-inf|-norm|-den)=0x1C : (+den|+norm|+inf)=0x380
  unsigned pdu[6];   // decoded-bit constant per phase
  u64 pdm[6];        // uniform mask: lanes with odd own-pred parity
  u64 mrx[2];        // permlane swap r.x-select masks
};

__device__ __forceinline__ void mk_sasb(int lane, int ph, float& sae, float& sbe, int& pdv) {
  pdv = par6(lane & CARR[ph]);
  int t = 0;
#pragma unroll
  for (int j = 0; j < 5; ++j) t |= par6(lane & CARR[(ph + 1 + j) % 6]) << j;
  t |= pdv << 5;
  const float sa = 1.0f - 2.0f * (float)par6(t & 45);   // poly 1011011
  const float sb = 1.0f - 2.0f * (float)par6(t & 60);   // poly 1111001
  sae = pdv ? -sa : sa;
  sbe = pdv ? -sb : sb;
}

__device__ __forceinline__ void mk_mrx(int lane, u64 (&mrx)[2]) {
  const u64 ODD16 = 0xFFFF0000FFFF0000ull, HI32 = 0xFFFFFFFF00000000ull;
#if __has_builtin(__builtin_amdgcn_permlane16_swap)
  {
    uint2v r = __builtin_amdgcn_permlane16_swap((unsigned)lane, (unsigned)lane, false, false);
    mrx[0] = (((unsigned)__builtin_amdgcn_readlane((int)r.x, 0) == 16u)) ? ~ODD16 : ODD16;
  }
#else
  mrx[0] = 0;
#endif
#if __has_builtin(__builtin_amdgcn_permlane32_swap)
  {
    uint2v r = __builtin_amdgcn_permlane32_swap((unsigned)lane, (unsigned)lane, false, false);
    mrx[1] = (((unsigned)__builtin_amdgcn_readlane((int)r.x, 0) == 32u)) ? ~HI32 : HI32;
  }
#else
  mrx[1] = 0;
#endif
}

__device__ __forceinline__ void mkconsts(int lane, Phc& p) {
#pragma unroll
  for (int ph = 0; ph < 6; ++ph) {
    int pdv;
    mk_sasb(lane, ph, p.sae[ph], p.sbe[ph], pdv);
    p.clsm[ph] = pdv ? 0x01Cu : 0x380u;
    p.pdu[ph] = (unsigned)pdv;
    p.pdm[ph] = __ballot(pdv != 0);
  }
  mk_mrx(lane, p.mrx);
}

// ---- hoisted branch metrics for a chunk (independent ILP block) ----
template<int N>
__device__ __forceinline__ void bmcalc(const float4 (&fy)[12], float (&bm)[24],
                                       const float (&sae)[6], const float (&sbe)[6]) {
#pragma unroll
  for (int k = 0; k < N; ++k) {
    const int ph = k % 6;
    const float y0 = (k & 1) ? fy[k >> 1].z : fy[k >> 1].x;
    const float y1 = (k & 1) ? fy[k >> 1].w : fy[k >> 1].y;
    bm[k] = fmaf(sae[ph], y0, sbe[ph] * y1);   // bit-exact vs ref
  }
}

// ---- forward core: N ACS steps; dw = 2*dw + d (d_K lands at bit N-1-K) ----
// d via v_cmp_class(D, clsm): per-lane direction, tie(+-0) -> 0. == verified sign-xor rule.
template<int N, int K>
__device__ __forceinline__ void acs(float& cum, unsigned& dw, const float (&bm)[24],
                                    const unsigned (&clsm)[6], const u64 (&mrx)[2]) {
  if constexpr (K < N) {
    constexpr int ph = K % 6;
    const float ex = exchf<ph>(cum, mrx);
    const float cA = cum + bm[K];   // own-pred candidate
    const float cB = ex - bm[K];    // partner-pred candidate
    const float D = cA - cB;        // sign exact; zero iff true tie
    cum = fminf(cA, cB);
    asm("v_cmp_class_f32 vcc, %1, %2\n\t"
        "v_addc_co_u32 %0, vcc, %0, %0, vcc"
        : "+v"(dw) : "v"(D), "v"(clsm[ph]) : "vcc");
    acs<N, K + 1>(cum, dw, bm, clsm, mrx);
  }
}

// ---- chunk word reconstruction from d-bits (tp = d XOR pd; verified r10-r14) ----
template<int N, int K>
__device__ __forceinline__ void wrec(unsigned& word, unsigned& dws, const unsigned (&pdu)[6],
                                     const u64 (&pdm)[6], const u64 (&mrx)[2]) {
  if constexpr (K < N) {
    constexpr int ph = K % 6;
    const unsigned exw = exchu<ph>(word, mrx);
    asm("v_cmp_gt_i32 vcc, 0, %1\n\t"
        "v_add_u32 %1, %1, %1\n\t"
        "s_xor_b64 vcc, vcc, %3\n\t"
        "v_cndmask_b32 %0, %0, %2, vcc"
        : "+v"(word), "+v"(dws)
        : "v"(exw), "s"(pdm[ph]) : "vcc");
    word |= pdu[ph] << (6 + K);
    wrec<N, K + 1>(word, dws, pdu, pdm, mrx);
  }
}

// ---- terminal argmin over true states (tie -> smallest state) ----
__device__ __forceinline__ int term_argmin(float cum, int lane) {
  // final labeling = phase 2048%6 = 2: state bit j from C[(2+j)%6] = {12,8,16,32,5,6}
  const int stf = par6(lane & 12) | (par6(lane & 8) << 1) | (par6(lane & 16) << 2) |
                  (par6(lane & 32) << 3) | (par6(lane & 5) << 4) | (par6(lane & 6) << 5);
  float v = cum; int bs = stf; int bl = lane;
#pragma unroll
  for (int off = 32; off >= 1; off >>= 1) {
    const float ov = __shfl_xor(v, off, 64);
    const int os = __shfl_xor(bs, off, 64);
    const int ol = __shfl_xor(bl, off, 64);
    if (ov < v || (ov == v && os < bs)) { v = ov; bs = os; bl = ol; }
  }
  return bl;
}

// ========== fused kernel: wave0 forward -> 8-wave wrec (in-place) -> wave0 traceback ==========
__global__ __launch_bounds__(512, 1) void vit_all(const float* __restrict__ in,
                                                  float* __restrict__ out) {
  __shared__ float y_lds[2 * T_STEPS];     // 16 KB staged input row
  __shared__ unsigned buf[NCHUNK][64];     // 21.5 KB: d-words, then path/anc words (in-place)
  __shared__ int lam_sh;

  const int tid = threadIdx.x;
  const int lane = tid & 63;
  const int wv = tid >> 6;
  const int b = blockIdx.x;

  // ---- stage y (8 waves, coalesced float4) ----
  {
    const float4* g = (const float4*)(in + (size_t)b * (2 * T_STEPS));
    float4* l = (float4*)y_lds;
    l[tid] = g[tid];
    l[tid + 512] = g[tid + 512];
  }
  Phc p;
  mkconsts(lane, p);
  __syncthreads();

  // ---- forward ACS (wave0 only; other waves wait, consuming no issue slots) ----
  if (wv == 0) {
    float cum = (lane == 0) ? 0.0f : LARGEF;
    float bm[24];
    float4 cur[12], nxt[12];
    const float4* y4 = (const float4*)y_lds;
    unsigned dw;
#pragma unroll
    for (int j = 0; j < 12; ++j) cur[j] = y4[j];               // chunk 0
    for (int cc = 0; cc < 42; ++cc) {
      const int c0 = 2 * cc;
      bmcalc<24>(cur, bm, p.sae, p.sbe);
#pragma unroll
      for (int j = 0; j < 12; ++j) nxt[j] = y4[12 * (c0 + 1) + j];   // prefetch c0+1
      dw = 0; acs<24, 0>(cum, dw, bm, p.clsm, p.mrx);
      buf[c0][lane] = dw;
      bmcalc<24>(nxt, bm, p.sae, p.sbe);
#pragma unroll
      for (int j = 0; j < 12; ++j) cur[j] = y4[12 * (c0 + 2) + j];   // prefetch c0+2
      dw = 0; acs<24, 0>(cum, dw, bm, p.clsm, p.mrx);
      buf[c0 + 1][lane] = dw;
    }
    // chunk 84 from cur; tail (steps 2040..2047) = float4 idx 1020..1023
    bmcalc<24>(cur, bm, p.sae, p.sbe);
#pragma unroll
    for (int j = 0; j < 4; ++j) nxt[j] = y4[1020 + j];
    dw = 0; acs<24, 0>(cum, dw, bm, p.clsm, p.mrx);
    buf[84][lane] = dw;
    bmcalc<8>(nxt, bm, p.sae, p.sbe);
    dw = 0; acs<8, 0>(cum, dw, bm, p.clsm, p.mrx);
    buf[85][lane] = dw;

    const int bl = term_argmin(cum, lane);
    if (lane == 0) lam_sh = bl;
  }
  __syncthreads();

  // ---- word reconstruction: 8 waves, ~11 chunks each, in-place on buf ----
  {
    const int cbeg = wv * 11;
    const int cend = (cbeg + 11 < NCHUNK) ? cbeg + 11 : NCHUNK;
    for (int c = cbeg; c < cend; ++c) {
      const unsigned dw = buf[c][lane];     // each slot read once, written once, same thread
      unsigned word = (unsigned)lane;
      if (c == NCHUNK - 1) {
        unsigned dws = dw << 24;
        wrec<8, 0>(word, dws, p.pdu, p.pdm, p.mrx);
      } else {
        unsigned dws = dw << 8;
        wrec<24, 0>(word, dws, p.pdu, p.pdm, p.mrx);
      }
      buf[c][lane] = word;
    }
  }
  __syncthreads();

  // ---- traceback: wave0, 86 chunk hops with prefetch ----
  if (wv == 0) {
    int lam = __builtin_amdgcn_readfirstlane(lam_sh);
    const size_t ob = (size_t)b * T_STEPS;
    unsigned row = buf[NCHUNK - 1][lane];
    for (int c = NCHUNK - 1; c >= 0; --c) {
      unsigned nrow = 0;
      if (c > 0) nrow = buf[c - 1][lane];          // prefetch (addr indep of lam)
      const unsigned w = (unsigned)__builtin_amdgcn_readlane((int)row, lam);
      const int nb = (c == NCHUNK - 1) ? 8 : 24;
      if (lane < nb) out[ob + c * 24 + lane] = (float)((w >> (6 + lane)) & 1u);
      lam = (int)(w & 63u);
      row = nrow;
    }
  }
}

extern "C" void kernel_launch(void* const* d_in, const int* in_sizes, int n_in,
                              void* d_out, int out_size, void* d_ws, size_t ws_size,
                              hipStream_t stream) {
  const float* in = (const float*)d_in[0];
  float* out = (float*)d_out;
  (void)in_sizes; (void)n_in; (void)out_size; (void)d_ws; (void)ws_size;
  vit_all<<<dim3(NB), dim3(512), 0, stream>>>(in, out);
}